// Round 1
// baseline (15567.085 us; speedup 1.0000x reference)
//
#include <hip/hip_runtime.h>
#include <cstdint>
#include <cstddef>

#define Hdim 512
#define Tdim 512
#define Bdim 32
#define NWG  256
#define SCAN_THREADS 384
// LDS: W 128*48 float4 (98304B) + h 4*129 float4 (8256B) + hp 192f (768B) + bhh 48f (192B)
#define SCAN_SMEM 107520

__device__ __forceinline__ float sigmoidf_(float v) {
    return 1.f / (1.f + __expf(-v));
}
__device__ __forceinline__ float tanhf_(float a) {
    float ax = fabsf(a);
    float e  = __expf(-2.f * ax);
    float t  = (1.f - e) / (1.f + e);
    return copysignf(t, a);
}

// ---------------------------------------------------------------------------
// Recurrent scan. 256 WGs, cooperative. WG = (unit-group u of 16 units) x
// (batch-group bg of 4 batches). W_hh slice (48 rows) lives in LDS for the
// whole kernel. Per step: device barrier via flags, gather h (agent atomics),
// 192 dots (split-k2 over 384 threads), gate math, scatter h_next.
// h is double-buffered: step t reads hbuf[t&1], writes hbuf[(t+1)&1].
// ---------------------------------------------------------------------------
__global__ void __launch_bounds__(SCAN_THREADS, 1)
gru_scan(const float* __restrict__ xp,    // [B][Tc][3H]
         const float* __restrict__ Whh,   // [3H][H]
         const float* __restrict__ bhh,   // [3H]
         const int*   __restrict__ lens,  // [B]
         float*       __restrict__ y,     // [B][T][H]
         float*       hbuf,               // [2][B][H]
         unsigned int* flags,             // [NWG]
         int t0, int Tc)
{
    extern __shared__ float smem[];
    float4* Wl4 = (float4*)smem;          // [128][48]  Wl4[k4*48+r] = W[row(r)][4k4..]
    float4* hl4 = Wl4 + 6144;             // [4][129]   h per batch, float4, padded
    float*  hps = (float*)(hl4 + 516);    // [48*4]     dot results
    float*  bhl = hps + 192;              // [48]

    const int tid = threadIdx.x;
    const int wg  = blockIdx.x;
    const int u   = wg & 31;
    const int bg  = wg >> 5;
    const int j0  = u << 4;
    const int b0  = bg << 2;

    // one-time: stage W slice (rows r = g*16+jl -> global row g*512 + j0 + jl)
    for (int i = tid; i < 48 * 128; i += SCAN_THREADS) {
        int r   = i >> 7;
        int k4  = i & 127;
        int grow = ((r >> 4) << 9) + j0 + (r & 15);
        float4 w = *(const float4*)(Whh + ((size_t)grow << 9) + (k4 << 2));
        Wl4[k4 * 48 + r] = w;
    }
    if (tid < 48) bhl[tid] = bhh[((tid >> 4) << 9) + j0 + (tid & 15)];

    const int r  = tid >> 3;        // [0,48) row within slice
    const int bl = (tid >> 1) & 3;  // [0,4)  local batch
    const int kh = tid & 1;         // k-half
    const bool isGate = tid < 64;
    const int gjl = tid & 15;
    const int gb  = (tid >> 4) & 3;
    int glen = 0;
    if (isGate) glen = lens[b0 + gb];
    const int jg = j0 + gjl;
    float* hlf = (float*)hl4;
    __syncthreads();

    for (int t = t0; t < t0 + Tc; ++t) {
        // ---- device-wide barrier: wait until all WGs finished step t-1 ----
        if (t > 0) {
            if (tid < 64) {
                const unsigned tgt = (unsigned)t;
                bool ok;
                do {
                    unsigned f0 = __hip_atomic_load(flags + tid * 4 + 0, __ATOMIC_RELAXED, __HIP_MEMORY_SCOPE_AGENT);
                    unsigned f1 = __hip_atomic_load(flags + tid * 4 + 1, __ATOMIC_RELAXED, __HIP_MEMORY_SCOPE_AGENT);
                    unsigned f2 = __hip_atomic_load(flags + tid * 4 + 2, __ATOMIC_RELAXED, __HIP_MEMORY_SCOPE_AGENT);
                    unsigned f3 = __hip_atomic_load(flags + tid * 4 + 3, __ATOMIC_RELAXED, __HIP_MEMORY_SCOPE_AGENT);
                    ok = (f0 >= tgt) & (f1 >= tgt) & (f2 >= tgt) & (f3 >= tgt);
                } while (!__all(ok));
                __threadfence();
            }
            __syncthreads();
        }

        // xp prefetch (consumed at gate stage)
        float xr = 0.f, xz = 0.f, xn = 0.f;
        if (isGate) {
            const float* xpb = xp + ((size_t)(b0 + gb) * Tc + (t - t0)) * 1536;
            xr = xpb[jg];
            xz = xpb[512 + jg];
            xn = xpb[1024 + jg];
        }

        // ---- gather h for our 4 batches into LDS (padded float4 rows) ----
        const float* hsrc = hbuf + (size_t)(t & 1) * (Bdim * Hdim);
        for (int i = tid; i < 4 * Hdim; i += SCAN_THREADS) {
            int b = i >> 9, k = i & 511;
            float v = __hip_atomic_load(hsrc + ((size_t)(b0 + b) << 9) + k,
                                        __ATOMIC_RELAXED, __HIP_MEMORY_SCOPE_AGENT);
            hlf[b * 516 + k] = v;
        }
        __syncthreads();

        // ---- dots: thread = (r, bl, kh); half-dot of length 256 ----
        const float4* wbase = Wl4 + (kh << 6) * 48 + r;
        const float4* hbase = hl4 + bl * 129 + (kh << 6);
        float4 s0 = {0.f, 0.f, 0.f, 0.f}, s1 = {0.f, 0.f, 0.f, 0.f};
#pragma unroll 4
        for (int k4 = 0; k4 < 64; k4 += 2) {
            float4 w0 = wbase[k4 * 48];
            float4 h0 = hbase[k4];
            float4 w1 = wbase[(k4 + 1) * 48];
            float4 h1 = hbase[k4 + 1];
            s0.x = fmaf(w0.x, h0.x, s0.x);
            s0.y = fmaf(w0.y, h0.y, s0.y);
            s0.z = fmaf(w0.z, h0.z, s0.z);
            s0.w = fmaf(w0.w, h0.w, s0.w);
            s1.x = fmaf(w1.x, h1.x, s1.x);
            s1.y = fmaf(w1.y, h1.y, s1.y);
            s1.z = fmaf(w1.z, h1.z, s1.z);
            s1.w = fmaf(w1.w, h1.w, s1.w);
        }
        float dot = (s0.x + s1.x) + (s0.y + s1.y) + ((s0.z + s1.z) + (s0.w + s1.w));
        dot += __shfl_xor(dot, 1);
        if (kh == 0) hps[r * 4 + bl] = dot;
        __syncthreads();

        // ---- gate math + outputs (64 threads) ----
        if (isGate) {
            float hr = hps[gjl * 4 + gb]        + bhl[gjl];
            float hz = hps[(16 + gjl) * 4 + gb] + bhl[16 + gjl];
            float hn = hps[(32 + gjl) * 4 + gb] + bhl[32 + gjl];
            float hold = hlf[gb * 516 + jg];
            float rg = sigmoidf_(xr + hr);
            float zg = sigmoidf_(xz + hz);
            float ng = tanhf_(xn + rg * hn);
            float hnew = (1.f - zg) * ng + zg * hold;
            bool m = t < glen;
            float hnext = m ? hnew : hold;
            float yv    = m ? hnew : 0.f;
            y[((size_t)(b0 + gb) * Tdim + t) * Hdim + jg] = yv;
            __hip_atomic_store(hbuf + (size_t)((t + 1) & 1) * (Bdim * Hdim) +
                               ((size_t)(b0 + gb) << 9) + jg,
                               hnext, __ATOMIC_RELAXED, __HIP_MEMORY_SCOPE_AGENT);
        }
        __syncthreads();   // drains all threads' stores (vmcnt(0) before s_barrier)
        if (tid == 0)
            __hip_atomic_store(flags + wg, (unsigned)(t + 1),
                               __ATOMIC_RELEASE, __HIP_MEMORY_SCOPE_AGENT);
    }
}

// ---------------------------------------------------------------------------
// fp32 NT-GEMM: C[m][n] = sum_k A[row(m)][k]*W[n][k] + bias[n]
// A is [B][Tsrc][H] with row(m) = (m>>tcLog)*Tdim + t0 + (m & (Tc-1)).
// 128x128 tile, BK=16, 256 threads, 8x8 micro-tile (split 4+4), prefetched.
// ---------------------------------------------------------------------------
#define FMA4(c, a, b) { (c).x = fmaf((a), (b).x, (c).x); (c).y = fmaf((a), (b).y, (c).y); \
                        (c).z = fmaf((a), (b).z, (c).z); (c).w = fmaf((a), (b).w, (c).w); }

__global__ void __launch_bounds__(256)
gemm_xproj(const float* __restrict__ A,
           const float* __restrict__ W,     // [1536][512]
           const float* __restrict__ bias,  // [1536]
           float* __restrict__ C,           // [B*Tc][1536]
           int tcLog, int t0)
{
    __shared__ float As[16][132];
    __shared__ float Bs[16][132];
    const int tid = threadIdx.x;
    const int n0  = blockIdx.x << 7;
    const int m0  = blockIdx.y << 7;
    const int tx  = tid & 15;
    const int ty  = tid >> 4;

    const int mrow = tid >> 2;
    const int kcol = (tid & 3) << 2;
    const int Tcm1 = (1 << tcLog) - 1;

    int mg0 = m0 + mrow;
    int mg1 = m0 + 64 + mrow;
    size_t srow0 = (size_t)(mg0 >> tcLog) * Tdim + t0 + (mg0 & Tcm1);
    size_t srow1 = (size_t)(mg1 >> tcLog) * Tdim + t0 + (mg1 & Tcm1);
    const float* Ap0 = A + srow0 * Hdim + kcol;
    const float* Ap1 = A + srow1 * Hdim + kcol;
    const float* Wp0 = W + (size_t)(n0 + mrow) * Hdim + kcol;
    const float* Wp1 = W + (size_t)(n0 + 64 + mrow) * Hdim + kcol;

    float4 c00[4], c01[4], c10[4], c11[4];
#pragma unroll
    for (int i = 0; i < 4; ++i) {
        c00[i] = {0.f,0.f,0.f,0.f}; c01[i] = {0.f,0.f,0.f,0.f};
        c10[i] = {0.f,0.f,0.f,0.f}; c11[i] = {0.f,0.f,0.f,0.f};
    }

    float4 a0 = *(const float4*)(Ap0);
    float4 a1 = *(const float4*)(Ap1);
    float4 b0 = *(const float4*)(Wp0);
    float4 b1 = *(const float4*)(Wp1);

    for (int kt = 0; kt < 512; kt += 16) {
        __syncthreads();
        As[kcol+0][mrow] = a0.x; As[kcol+1][mrow] = a0.y;
        As[kcol+2][mrow] = a0.z; As[kcol+3][mrow] = a0.w;
        As[kcol+0][mrow+64] = a1.x; As[kcol+1][mrow+64] = a1.y;
        As[kcol+2][mrow+64] = a1.z; As[kcol+3][mrow+64] = a1.w;
        Bs[kcol+0][mrow] = b0.x; Bs[kcol+1][mrow] = b0.y;
        Bs[kcol+2][mrow] = b0.z; Bs[kcol+3][mrow] = b0.w;
        Bs[kcol+0][mrow+64] = b1.x; Bs[kcol+1][mrow+64] = b1.y;
        Bs[kcol+2][mrow+64] = b1.z; Bs[kcol+3][mrow+64] = b1.w;
        __syncthreads();
        if (kt + 16 < 512) {
            a0 = *(const float4*)(Ap0 + kt + 16);
            a1 = *(const float4*)(Ap1 + kt + 16);
            b0 = *(const float4*)(Wp0 + kt + 16);
            b1 = *(const float4*)(Wp1 + kt + 16);
        }
#pragma unroll
        for (int kk = 0; kk < 16; ++kk) {
            float4 aA = *(const float4*)&As[kk][ty * 4];
            float4 aB = *(const float4*)&As[kk][64 + ty * 4];
            float4 bA = *(const float4*)&Bs[kk][tx * 4];
            float4 bB = *(const float4*)&Bs[kk][64 + tx * 4];
            FMA4(c00[0], aA.x, bA); FMA4(c01[0], aA.x, bB);
            FMA4(c00[1], aA.y, bA); FMA4(c01[1], aA.y, bB);
            FMA4(c00[2], aA.z, bA); FMA4(c01[2], aA.z, bB);
            FMA4(c00[3], aA.w, bA); FMA4(c01[3], aA.w, bB);
            FMA4(c10[0], aB.x, bA); FMA4(c11[0], aB.x, bB);
            FMA4(c10[1], aB.y, bA); FMA4(c11[1], aB.y, bB);
            FMA4(c10[2], aB.z, bA); FMA4(c11[2], aB.z, bB);
            FMA4(c10[3], aB.w, bA); FMA4(c11[3], aB.w, bB);
        }
    }

    float4 biasA = *(const float4*)(bias + n0 + tx * 4);
    float4 biasB = *(const float4*)(bias + n0 + 64 + tx * 4);
#pragma unroll
    for (int i = 0; i < 4; ++i) {
        size_t row0 = (size_t)m0 + ty * 4 + i;
        size_t row1 = row0 + 64;
        float4 v;
        v.x = c00[i].x + biasA.x; v.y = c00[i].y + biasA.y;
        v.z = c00[i].z + biasA.z; v.w = c00[i].w + biasA.w;
        *(float4*)(C + row0 * 1536 + n0 + tx * 4) = v;
        v.x = c01[i].x + biasB.x; v.y = c01[i].y + biasB.y;
        v.z = c01[i].z + biasB.z; v.w = c01[i].w + biasB.w;
        *(float4*)(C + row0 * 1536 + n0 + 64 + tx * 4) = v;
        v.x = c10[i].x + biasA.x; v.y = c10[i].y + biasA.y;
        v.z = c10[i].z + biasA.z; v.w = c10[i].w + biasA.w;
        *(float4*)(C + row1 * 1536 + n0 + tx * 4) = v;
        v.x = c11[i].x + biasB.x; v.y = c11[i].y + biasB.y;
        v.z = c11[i].z + biasB.z; v.w = c11[i].w + biasB.w;
        *(float4*)(C + row1 * 1536 + n0 + 64 + tx * 4) = v;
    }
}

// ---------------------------------------------------------------------------
extern "C" void kernel_launch(void* const* d_in, const int* in_sizes, int n_in,
                              void* d_out, int out_size, void* d_ws, size_t ws_size,
                              hipStream_t stream) {
    (void)in_sizes; (void)n_in; (void)out_size;
    const float* x    = (const float*)d_in[0];
    const int*   lens = (const int*)d_in[1];
    const float* Wih0 = (const float*)d_in[2];
    const float* Whh0 = (const float*)d_in[3];
    const float* bih0 = (const float*)d_in[4];
    const float* bhh0 = (const float*)d_in[5];
    const float* Wih1 = (const float*)d_in[6];
    const float* Whh1 = (const float*)d_in[7];
    const float* bih1 = (const float*)d_in[8];
    const float* bhh1 = (const float*)d_in[9];
    float* out = (float*)d_out;

    // ws layout: [xp: B*Tc*1536 f32][hA: 2*B*H][hB: 2*B*H][flagsA: 256][flagsB: 256]
    const size_t ctrl_bytes = (size_t)(2 * 2 * Bdim * Hdim) * 4 + (size_t)(2 * NWG) * 4;
    int Tc = 512;
    while (Tc > 4 && (size_t)Bdim * Tc * 1536 * 4 + ctrl_bytes > ws_size) Tc >>= 1;
    int tcLog = 31 - __builtin_clz((unsigned)Tc);
    size_t xp_bytes = (size_t)Bdim * Tc * 1536 * 4;

    float* xp = (float*)d_ws;
    char*  ctrl = (char*)d_ws + xp_bytes;
    float* hA = (float*)ctrl;
    float* hB = hA + 2 * Bdim * Hdim;
    unsigned int* flagsA = (unsigned int*)(hB + 2 * Bdim * Hdim);
    unsigned int* flagsB = flagsA + NWG;

    hipMemsetAsync(ctrl, 0, ctrl_bytes, stream);
    hipFuncSetAttribute((const void*)gru_scan,
                        hipFuncAttributeMaxDynamicSharedMemorySize, SCAN_SMEM);

    for (int layer = 0; layer < 2; ++layer) {
        const float* src  = layer ? (const float*)out : x;
        const float* Wih  = layer ? Wih1 : Wih0;
        const float* bih  = layer ? bih1 : bih0;
        const float* Whh  = layer ? Whh1 : Whh0;
        const float* bhhp = layer ? bhh1 : bhh0;
        float* hbuf = layer ? hB : hA;
        unsigned int* flags = layer ? flagsB : flagsA;

        for (int t0 = 0; t0 < Tdim; t0 += Tc) {
            dim3 gg(12, (Bdim * Tc) >> 7);
            gemm_xproj<<<gg, dim3(256), 0, stream>>>(src, Wih, bih, xp, tcLog, t0);

            const float* a_xp  = xp;
            const float* a_whh = Whh;
            const float* a_bhh = bhhp;
            const int*   a_ln  = lens;
            float*       a_y   = out;
            float*       a_h   = hbuf;
            unsigned int* a_fl = flags;
            int a_t0 = t0;
            int a_tc = Tc;
            void* args[] = { &a_xp, &a_whh, &a_bhh, &a_ln, &a_y, &a_h, &a_fl, &a_t0, &a_tc };
            hipLaunchCooperativeKernel((const void*)gru_scan, dim3(NWG), dim3(SCAN_THREADS),
                                       args, SCAN_SMEM, stream);
        }
    }
}

// Round 3
// 7495.999 us; speedup vs baseline: 2.0767x; 2.0767x over previous
//
#include <hip/hip_runtime.h>
#include <cstdint>
#include <cstddef>

#define Hdim 512
#define Tdim 512
#define Bdim 32
#define NWG  256
#define SCAN_THREADS 384

typedef float f32x4 __attribute__((ext_vector_type(4)));

__device__ __forceinline__ float sigmoidf_(float v) {
    return 1.f / (1.f + __expf(-v));
}
__device__ __forceinline__ float tanhf_(float a) {
    float ax = fabsf(a);
    float e  = __expf(-2.f * ax);
    float t  = (1.f - e) / (1.f + e);
    return copysignf(t, a);
}

// ---------------------------------------------------------------------------
// Recurrent scan. 256 WGs cooperative. WG = (unit-group u: 16 units) x
// (batch-group bg: 4 batches). W_hh slice (48 rows x 512) lives in VGPRs:
// thread (rp in [0,24), kq in [0,16)) holds rows {rp, rp+24}, k-chunk
// kq*32..+32 (64 floats). Per step: relaxed spin on 256 flags, vectorized
// sc0sc1 gather of h into XOR-swizzled LDS, register dots + shfl reduce,
// gate math on wave 0, sc0sc1 float4 h-scatter, manual vmcnt(0), flag store.
// No fences, no release/acquire -> no per-step cache maintenance.
// ---------------------------------------------------------------------------
__global__ void __launch_bounds__(SCAN_THREADS, 1)
gru_scan(const float* __restrict__ xp,    // [B][Tc][3H]
         const float* __restrict__ Whh,   // [3H][H]
         const float* __restrict__ bhh,   // [3H]
         const int*   __restrict__ lens,  // [B]
         float*       __restrict__ y,     // [B][T][H]
         float*       hbuf,               // [2][B][H]
         unsigned int* flags,             // [NWG]
         int t0, int Tc)
{
    __shared__ float  hlf[4 * Hdim];      // h, per batch 128 float4, XOR-swizzled
    __shared__ float4 hps4[48];           // dot results: hps4[r] = {b0,b1,b2,b3}
    __shared__ float  hnext_s[64];        // gate outputs [4][16]

    const int tid = threadIdx.x;
    const int wg  = blockIdx.x;
    const int u   = wg & 31;
    const int bg  = wg >> 5;
    const int j0  = u << 4;
    const int b0  = bg << 2;

    const int rp = tid >> 4;        // [0,24)
    const int kq = tid & 15;        // [0,16)

    // ---- W_hh rows {rp, rp+24}, k-chunk kq*32, into registers ----
    float4 w0[8], w1[8];
    {
        int r0 = rp, r1 = rp + 24;
        int g0 = ((r0 >> 4) << 9) + j0 + (r0 & 15);
        int g1 = ((r1 >> 4) << 9) + j0 + (r1 & 15);
        const float* p0 = Whh + ((size_t)g0 << 9) + (kq << 5);
        const float* p1 = Whh + ((size_t)g1 << 9) + (kq << 5);
#pragma unroll
        for (int i = 0; i < 8; ++i) {
            w0[i] = *(const float4*)(p0 + (i << 2));
            w1[i] = *(const float4*)(p1 + (i << 2));
        }
    }

    // gate-thread constants (tid < 64): (gb, gjl)
    const bool isGate = tid < 64;
    const int gjl = tid & 15;
    const int gb  = (tid >> 4) & 3;
    const int jg  = j0 + gjl;
    int   glen = 0;
    float bh_r = 0.f, bh_z = 0.f, bh_n = 0.f;
    if (isGate) {
        glen = lens[b0 + gb];
        bh_r = bhh[jg];
        bh_z = bhh[512 + jg];
        bh_n = bhh[1024 + jg];
    }
    // hold read offsets (swizzled)
    int holdIdx = 0;
    if (isGate) {
        int L = jg >> 2, c = jg & 3;
        int P = L ^ ((L >> 3) & 7);
        holdIdx = (gb << 9) + (P << 2) + c;
    }

    // gather indices (tid < 256): two float4 each
    const int gi0 = tid;
    const int gi1 = tid + 256;
    const int gb0_ = gi0 >> 7, gL0 = gi0 & 127;
    const int gb1_ = gi1 >> 7, gL1 = gi1 & 127;
    const int gP0 = gL0 ^ ((gL0 >> 3) & 7);
    const int gP1 = gL1 ^ ((gL1 >> 3) & 7);
    float* ld0 = &hlf[(gb0_ << 9) + (gP0 << 2)];
    float* ld1 = &hlf[(gb1_ << 9) + (gP1 << 2)];

    for (int t = t0; t < t0 + Tc; ++t) {
        // xp prefetch (cached loads, issued before the spin)
        float xr = 0.f, xz = 0.f, xn = 0.f;
        if (isGate) {
            const float* xpb = xp + ((size_t)(b0 + gb) * Tc + (t - t0)) * 1536;
            xr = xpb[jg];
            xz = xpb[512 + jg];
            xn = xpb[1024 + jg];
        }

        // ---- spin: all 256 WGs finished step t-1 ----
        if (tid < 256) {
            const unsigned tgt = (unsigned)t;
            for (;;) {
                unsigned f = __hip_atomic_load(flags + tid, __ATOMIC_RELAXED,
                                               __HIP_MEMORY_SCOPE_AGENT);
                if (__all(f >= tgt)) break;
            }
        }
        __syncthreads();   // (a)

        // ---- gather h[4][512] -> swizzled LDS, sc0sc1 float4 loads ----
        if (tid < 256) {
            const float* hsrc = hbuf + (size_t)(t & 1) * (Bdim * Hdim);
            const float* s0 = hsrc + ((size_t)(b0 + gb0_) << 9) + (gL0 << 2);
            const float* s1 = hsrc + ((size_t)(b0 + gb1_) << 9) + (gL1 << 2);
            f32x4 v0, v1;
            asm volatile(
                "global_load_dwordx4 %0, %2, off sc0 sc1\n\t"
                "global_load_dwordx4 %1, %3, off sc0 sc1\n\t"
                "s_waitcnt vmcnt(0)"
                : "=&v"(v0), "=&v"(v1)
                : "v"(s0), "v"(s1)
                : "memory");
            *(f32x4*)ld0 = v0;
            *(f32x4*)ld1 = v1;
        }
        __syncthreads();   // (b)

        // ---- dots: rows {rp, rp+24} x 4 batches over k-chunk kq*32..+32 ----
        float acc0[4], acc1[4];
#pragma unroll
        for (int b = 0; b < 4; ++b) {
            const float4* hb = (const float4*)&hlf[b << 9];
            float a0 = 0.f, a1 = 0.f;
#pragma unroll
            for (int i = 0; i < 8; ++i) {
                float4 h = hb[(kq << 3) + (i ^ (kq & 7))];
                a0 = fmaf(w0[i].x, h.x, a0);
                a0 = fmaf(w0[i].y, h.y, a0);
                a0 = fmaf(w0[i].z, h.z, a0);
                a0 = fmaf(w0[i].w, h.w, a0);
                a1 = fmaf(w1[i].x, h.x, a1);
                a1 = fmaf(w1[i].y, h.y, a1);
                a1 = fmaf(w1[i].z, h.z, a1);
                a1 = fmaf(w1[i].w, h.w, a1);
            }
            acc0[b] = a0; acc1[b] = a1;
        }
        // reduce over kq (16 lanes)
#pragma unroll
        for (int m = 1; m <= 8; m <<= 1) {
#pragma unroll
            for (int b = 0; b < 4; ++b) {
                acc0[b] += __shfl_xor(acc0[b], m);
                acc1[b] += __shfl_xor(acc1[b], m);
            }
        }
        if (kq == 0) {
            hps4[rp]      = make_float4(acc0[0], acc0[1], acc0[2], acc0[3]);
            hps4[rp + 24] = make_float4(acc1[0], acc1[1], acc1[2], acc1[3]);
        }
        __syncthreads();   // (c)

        // ---- gate math (wave 0) ----
        if (isGate) {
            const float* hps = (const float*)hps4;
            float hr = hps[(gjl << 2) + gb]        + bh_r;
            float hz = hps[((16 + gjl) << 2) + gb] + bh_z;
            float hn = hps[((32 + gjl) << 2) + gb] + bh_n;
            float hold = hlf[holdIdx];
            float rg = sigmoidf_(xr + hr);
            float zg = sigmoidf_(xz + hz);
            float ng = tanhf_(xn + rg * hn);
            float hnew = (1.f - zg) * ng + zg * hold;
            bool m = t < glen;
            float hnext = m ? hnew : hold;
            y[((size_t)(b0 + gb) * Tdim + t) * Hdim + jg] = m ? hnew : 0.f;
            hnext_s[(gb << 4) + gjl] = hnext;
        }
        // tid<16 pack + sc0sc1 float4 scatter (same wave as gate: no barrier)
        if (tid < 16) {
            int bb = tid >> 2, q = tid & 3;
            f32x4 hv = *(f32x4*)&hnext_s[(bb << 4) + (q << 2)];
            float* dst = hbuf + (size_t)((t + 1) & 1) * (Bdim * Hdim) +
                         ((size_t)(b0 + bb) << 9) + j0 + (q << 2);
            asm volatile("global_store_dwordx4 %0, %1, off sc0 sc1"
                         :: "v"(dst), "v"(hv) : "memory");
        }
        asm volatile("s_waitcnt vmcnt(0)" ::: "memory");
        if (tid == 0)
            __hip_atomic_store(flags + wg, (unsigned)(t + 1),
                               __ATOMIC_RELAXED, __HIP_MEMORY_SCOPE_AGENT);
    }
}

// ---------------------------------------------------------------------------
// fp32 NT-GEMM: C[m][n] = sum_k A[row(m)][k]*W[n][k] + bias[n]  (unchanged)
// ---------------------------------------------------------------------------
#define FMA4(c, a, b) { (c).x = fmaf((a), (b).x, (c).x); (c).y = fmaf((a), (b).y, (c).y); \
                        (c).z = fmaf((a), (b).z, (c).z); (c).w = fmaf((a), (b).w, (c).w); }

__global__ void __launch_bounds__(256)
gemm_xproj(const float* __restrict__ A,
           const float* __restrict__ W,     // [1536][512]
           const float* __restrict__ bias,  // [1536]
           float* __restrict__ C,           // [B*Tc][1536]
           int tcLog, int t0)
{
    __shared__ float As[16][132];
    __shared__ float Bs[16][132];
    const int tid = threadIdx.x;
    const int n0  = blockIdx.x << 7;
    const int m0  = blockIdx.y << 7;
    const int tx  = tid & 15;
    const int ty  = tid >> 4;

    const int mrow = tid >> 2;
    const int kcol = (tid & 3) << 2;
    const int Tcm1 = (1 << tcLog) - 1;

    int mg0 = m0 + mrow;
    int mg1 = m0 + 64 + mrow;
    size_t srow0 = (size_t)(mg0 >> tcLog) * Tdim + t0 + (mg0 & Tcm1);
    size_t srow1 = (size_t)(mg1 >> tcLog) * Tdim + t0 + (mg1 & Tcm1);
    const float* Ap0 = A + srow0 * Hdim + kcol;
    const float* Ap1 = A + srow1 * Hdim + kcol;
    const float* Wp0 = W + (size_t)(n0 + mrow) * Hdim + kcol;
    const float* Wp1 = W + (size_t)(n0 + 64 + mrow) * Hdim + kcol;

    float4 c00[4], c01[4], c10[4], c11[4];
#pragma unroll
    for (int i = 0; i < 4; ++i) {
        c00[i] = {0.f,0.f,0.f,0.f}; c01[i] = {0.f,0.f,0.f,0.f};
        c10[i] = {0.f,0.f,0.f,0.f}; c11[i] = {0.f,0.f,0.f,0.f};
    }

    float4 a0 = *(const float4*)(Ap0);
    float4 a1 = *(const float4*)(Ap1);
    float4 b0 = *(const float4*)(Wp0);
    float4 b1 = *(const float4*)(Wp1);

    for (int kt = 0; kt < 512; kt += 16) {
        __syncthreads();
        As[kcol+0][mrow] = a0.x; As[kcol+1][mrow] = a0.y;
        As[kcol+2][mrow] = a0.z; As[kcol+3][mrow] = a0.w;
        As[kcol+0][mrow+64] = a1.x; As[kcol+1][mrow+64] = a1.y;
        As[kcol+2][mrow+64] = a1.z; As[kcol+3][mrow+64] = a1.w;
        Bs[kcol+0][mrow] = b0.x; Bs[kcol+1][mrow] = b0.y;
        Bs[kcol+2][mrow] = b0.z; Bs[kcol+3][mrow] = b0.w;
        Bs[kcol+0][mrow+64] = b1.x; Bs[kcol+1][mrow+64] = b1.y;
        Bs[kcol+2][mrow+64] = b1.z; Bs[kcol+3][mrow+64] = b1.w;
        __syncthreads();
        if (kt + 16 < 512) {
            a0 = *(const float4*)(Ap0 + kt + 16);
            a1 = *(const float4*)(Ap1 + kt + 16);
            b0 = *(const float4*)(Wp0 + kt + 16);
            b1 = *(const float4*)(Wp1 + kt + 16);
        }
#pragma unroll
        for (int kk = 0; kk < 16; ++kk) {
            float4 aA = *(const float4*)&As[kk][ty * 4];
            float4 aB = *(const float4*)&As[kk][64 + ty * 4];
            float4 bA = *(const float4*)&Bs[kk][tx * 4];
            float4 bB = *(const float4*)&Bs[kk][64 + tx * 4];
            FMA4(c00[0], aA.x, bA); FMA4(c01[0], aA.x, bB);
            FMA4(c00[1], aA.y, bA); FMA4(c01[1], aA.y, bB);
            FMA4(c00[2], aA.z, bA); FMA4(c01[2], aA.z, bB);
            FMA4(c00[3], aA.w, bA); FMA4(c01[3], aA.w, bB);
            FMA4(c10[0], aB.x, bA); FMA4(c11[0], aB.x, bB);
            FMA4(c10[1], aB.y, bA); FMA4(c11[1], aB.y, bB);
            FMA4(c10[2], aB.z, bA); FMA4(c11[2], aB.z, bB);
            FMA4(c10[3], aB.w, bA); FMA4(c11[3], aB.w, bB);
        }
    }

    float4 biasA = *(const float4*)(bias + n0 + tx * 4);
    float4 biasB = *(const float4*)(bias + n0 + 64 + tx * 4);
#pragma unroll
    for (int i = 0; i < 4; ++i) {
        size_t row0 = (size_t)m0 + ty * 4 + i;
        size_t row1 = row0 + 64;
        float4 v;
        v.x = c00[i].x + biasA.x; v.y = c00[i].y + biasA.y;
        v.z = c00[i].z + biasA.z; v.w = c00[i].w + biasA.w;
        *(float4*)(C + row0 * 1536 + n0 + tx * 4) = v;
        v.x = c01[i].x + biasB.x; v.y = c01[i].y + biasB.y;
        v.z = c01[i].z + biasB.z; v.w = c01[i].w + biasB.w;
        *(float4*)(C + row0 * 1536 + n0 + 64 + tx * 4) = v;
        v.x = c10[i].x + biasA.x; v.y = c10[i].y + biasA.y;
        v.z = c10[i].z + biasA.z; v.w = c10[i].w + biasA.w;
        *(float4*)(C + row1 * 1536 + n0 + tx * 4) = v;
        v.x = c11[i].x + biasB.x; v.y = c11[i].y + biasB.y;
        v.z = c11[i].z + biasB.z; v.w = c11[i].w + biasB.w;
        *(float4*)(C + row1 * 1536 + n0 + 64 + tx * 4) = v;
    }
}

// ---------------------------------------------------------------------------
extern "C" void kernel_launch(void* const* d_in, const int* in_sizes, int n_in,
                              void* d_out, int out_size, void* d_ws, size_t ws_size,
                              hipStream_t stream) {
    (void)in_sizes; (void)n_in; (void)out_size;
    const float* x    = (const float*)d_in[0];
    const int*   lens = (const int*)d_in[1];
    const float* Wih0 = (const float*)d_in[2];
    const float* Whh0 = (const float*)d_in[3];
    const float* bih0 = (const float*)d_in[4];
    const float* bhh0 = (const float*)d_in[5];
    const float* Wih1 = (const float*)d_in[6];
    const float* Whh1 = (const float*)d_in[7];
    const float* bih1 = (const float*)d_in[8];
    const float* bhh1 = (const float*)d_in[9];
    float* out = (float*)d_out;

    // ws layout: [xp: B*Tc*1536 f32][hA: 2*B*H][hB: 2*B*H][flagsA: 256][flagsB: 256]
    const size_t ctrl_bytes = (size_t)(2 * 2 * Bdim * Hdim) * 4 + (size_t)(2 * NWG) * 4;
    int Tc = 512;
    while (Tc > 4 && (size_t)Bdim * Tc * 1536 * 4 + ctrl_bytes > ws_size) Tc >>= 1;
    int tcLog = 31 - __builtin_clz((unsigned)Tc);
    size_t xp_bytes = (size_t)Bdim * Tc * 1536 * 4;

    float* xp = (float*)d_ws;
    char*  ctrl = (char*)d_ws + xp_bytes;
    float* hA = (float*)ctrl;
    float* hB = hA + 2 * Bdim * Hdim;
    unsigned int* flagsA = (unsigned int*)(hB + 2 * Bdim * Hdim);
    unsigned int* flagsB = flagsA + NWG;

    (void)hipMemsetAsync(ctrl, 0, ctrl_bytes, stream);

    for (int layer = 0; layer < 2; ++layer) {
        const float* src  = layer ? (const float*)out : x;
        const float* Wih  = layer ? Wih1 : Wih0;
        const float* bih  = layer ? bih1 : bih0;
        const float* Whh  = layer ? Whh1 : Whh0;
        const float* bhhp = layer ? bhh1 : bhh0;
        float* hbuf = layer ? hB : hA;
        unsigned int* flags = layer ? flagsB : flagsA;

        for (int t0 = 0; t0 < Tdim; t0 += Tc) {
            dim3 gg(12, (Bdim * Tc) >> 7);
            gemm_xproj<<<gg, dim3(256), 0, stream>>>(src, Wih, bih, xp, tcLog, t0);

            const float* a_xp  = xp;
            const float* a_whh = Whh;
            const float* a_bhh = bhhp;
            const int*   a_ln  = lens;
            float*       a_y   = out;
            float*       a_h   = hbuf;
            unsigned int* a_fl = flags;
            int a_t0 = t0;
            int a_tc = Tc;
            void* args[] = { &a_xp, &a_whh, &a_bhh, &a_ln, &a_y, &a_h, &a_fl, &a_t0, &a_tc };
            (void)hipLaunchCooperativeKernel((const void*)gru_scan, dim3(NWG), dim3(SCAN_THREADS),
                                             args, 0, stream);
        }
    }
}

// Round 5
// 3656.393 us; speedup vs baseline: 4.2575x; 2.0501x over previous
//
#include <hip/hip_runtime.h>
#include <cstdint>
#include <cstddef>

#define Hdim 512
#define Tdim 512
#define Bdim 32
#define NWG  256
#define SCAN_THREADS 384

typedef float        f32x4 __attribute__((ext_vector_type(4)));
typedef unsigned int u32x4 __attribute__((ext_vector_type(4)));
typedef unsigned int u32x2 __attribute__((ext_vector_type(2)));

__device__ __forceinline__ float sigmoidf_(float v) {
    return 1.f / (1.f + __expf(-v));
}
__device__ __forceinline__ float tanhf_(float a) {
    float ax = fabsf(a);
    float e  = __expf(-2.f * ax);
    float t  = (1.f - e) / (1.f + e);
    return copysignf(t, a);
}

// ---------------------------------------------------------------------------
// Tag-fused exchange GRU scan.
// WG = (bg = wg>>5: 4 batches) x (u = wg&31: 16 units x 3 gates = 48 W-rows
// in VGPRs; thread (rp,kq) holds rows {rp,rp+24}, k-chunk kq*32..+32).
// h exchange: uint2 {h_bits, tag=t} per (batch,k). Producers store dwordx2
// sc0 sc1; consumers poll dwordx4 loads until all 8 tags == t (data arrives
// fused with the tags -> ONE coherence round trip per step).
// Ping-pong: step t reads buf[t&1] (tag t), writes buf[(t+1)&1] (tag t+1).
// Safety: a WG can pass step-t's poll only after every peer stored tag t,
// which (program order + vmcnt) implies every peer finished its step-(t-1)
// reads of buf[(t+1)&1] -> overwrite is race-free.
// ---------------------------------------------------------------------------
__global__ void __launch_bounds__(SCAN_THREADS, 1)
gru_scan(const float* __restrict__ xp,    // [B][Tc][3H]
         const float* __restrict__ Whh,   // [3H][H]
         const float* __restrict__ bhh,   // [3H]
         const int*   __restrict__ lens,  // [B]
         float*       __restrict__ y,     // [B][T][H]
         u32x2*       hb2,                // [2][8][2048] {h,tag}
         int t0, int Tc)
{
    __shared__ float  hlf[4 * Hdim];     // h (XOR-swizzled quads), 8 KB
    __shared__ float4 part4[16 * 49];    // dot partials [kq][row(48,pad49)]
    __shared__ float  dummy_guard[4];    // (unused)

    const int tid = threadIdx.x;
    const int wg  = blockIdx.x;
    const int u   = wg & 31;
    const int bg  = wg >> 5;
    const int j0  = u << 4;
    const int b0  = bg << 2;
    const int rp  = tid >> 4;        // [0,24)
    const int kq  = tid & 15;        // [0,16)

    // ---- W_hh rows {rp, rp+24}, k-chunk kq*32, into registers ----
    float4 w0[8], w1[8];
    {
        int g0 = ((rp >> 4) << 9) + j0 + (rp & 15);
        int r1 = rp + 24;
        int g1 = ((r1 >> 4) << 9) + j0 + (r1 & 15);
        const float* p0 = Whh + ((size_t)g0 << 9) + (kq << 5);
        const float* p1 = Whh + ((size_t)g1 << 9) + (kq << 5);
#pragma unroll
        for (int i = 0; i < 8; ++i) {
            w0[i] = *(const float4*)(p0 + (i << 2));
            w1[i] = *(const float4*)(p1 + (i << 2));
        }
    }

    const bool isGate = tid < 64;
    const int gjl = tid & 15;
    const int gb  = (tid >> 4) & 3;
    const int jg  = j0 + gjl;
    int   glen = 0;
    float bh_r = 0.f, bh_z = 0.f, bh_n = 0.f;
    int holdIdx = 0;
    const float* xpb = nullptr;
    if (isGate) {
        glen = lens[b0 + gb];
        bh_r = bhh[jg];
        bh_z = bhh[512 + jg];
        bh_n = bhh[1024 + jg];
        int L = jg >> 2, c = jg & 3;
        int P = L ^ ((L >> 3) & 7);
        holdIdx = (gb << 9) + (P << 2) + c;
        xpb = xp + (size_t)(b0 + gb) * Tc * 1536;
    }

    // consumer poll constants (tid < 256): 8 {h,tag} pairs starting at tid*8
    const bool isPoll = tid < 256;
    const int  pb  = tid >> 6;                 // local batch of my pairs
    const int  pL  = (tid & 63) << 1;          // even quad index within batch
    const int  pP0 = pL ^ ((pL >> 3) & 7);     // swizzled quad for pL
    const int  pP1 = pP0 ^ 1;                  // swizzled quad for pL+1
    float* lds_w0 = &hlf[(pb << 9) + (pP0 << 2)];
    float* lds_w1 = &hlf[(pb << 9) + (pP1 << 2)];

    // xp values for step t0
    float xr = 0.f, xz = 0.f, xn = 0.f;
    if (isGate) {
        xr = xpb[jg];
        xz = xpb[512 + jg];
        xn = xpb[1024 + jg];
    }

    int budget = 1 << 20;   // safety: fail fast instead of hanging

    for (int t = t0; t < t0 + Tc; ++t) {
        const unsigned tg = (unsigned)t;

        // ---- poll buf[t&1] until all 8 tags == t; h arrives with tags ----
        if (isPoll) {
            const u32x2* src = hb2 + ((size_t)(t & 1) << 14) + (bg << 11) + (tid << 3);
            u32x4 q0, q1, q2, q3;
            for (;;) {
                asm volatile(
                    "global_load_dwordx4 %0, %4, off sc0 sc1\n\t"
                    "global_load_dwordx4 %1, %4, off offset:16 sc0 sc1\n\t"
                    "global_load_dwordx4 %2, %4, off offset:32 sc0 sc1\n\t"
                    "global_load_dwordx4 %3, %4, off offset:48 sc0 sc1\n\t"
                    "s_waitcnt vmcnt(0)"
                    : "=&v"(q0), "=&v"(q1), "=&v"(q2), "=&v"(q3)
                    : "v"(src) : "memory");
                bool ok = (q0[1] == tg) & (q0[3] == tg) & (q1[1] == tg) & (q1[3] == tg) &
                          (q2[1] == tg) & (q2[3] == tg) & (q3[1] == tg) & (q3[3] == tg);
                if (__all(ok)) break;
                if (--budget < 0) break;
            }
            f32x4 h0 = { __uint_as_float(q0[0]), __uint_as_float(q0[2]),
                         __uint_as_float(q1[0]), __uint_as_float(q1[2]) };
            f32x4 h1 = { __uint_as_float(q2[0]), __uint_as_float(q2[2]),
                         __uint_as_float(q3[0]), __uint_as_float(q3[2]) };
            *(f32x4*)lds_w0 = h0;
            *(f32x4*)lds_w1 = h1;
        }
        // next-step xp prefetch (issue now, consume next iteration)
        float xrn = 0.f, xzn = 0.f, xnn = 0.f;
        if (isGate) {
            int tf = (t + 1 < t0 + Tc) ? (t + 1 - t0) : (t - t0);
            const float* xq = xpb + (size_t)tf * 1536;
            xrn = xq[jg];
            xzn = xq[512 + jg];
            xnn = xq[1024 + jg];
        }
        __syncthreads();   // (b) h in LDS

        // ---- dots: rows {rp, rp+24} x 4 batches over k-chunk kq*32..+32 ----
        float acc0[4], acc1[4];
#pragma unroll
        for (int b = 0; b < 4; ++b) {
            const float4* hb = (const float4*)&hlf[b << 9];
            float a0 = 0.f, a1 = 0.f;
#pragma unroll
            for (int i = 0; i < 8; ++i) {
                float4 h = hb[(kq << 3) + (i ^ (kq & 7))];
                a0 = fmaf(w0[i].x, h.x, a0);
                a0 = fmaf(w0[i].y, h.y, a0);
                a0 = fmaf(w0[i].z, h.z, a0);
                a0 = fmaf(w0[i].w, h.w, a0);
                a1 = fmaf(w1[i].x, h.x, a1);
                a1 = fmaf(w1[i].y, h.y, a1);
                a1 = fmaf(w1[i].z, h.z, a1);
                a1 = fmaf(w1[i].w, h.w, a1);
            }
            acc0[b] = a0; acc1[b] = a1;
        }
        part4[kq * 49 + rp]      = make_float4(acc0[0], acc0[1], acc0[2], acc0[3]);
        part4[kq * 49 + rp + 24] = make_float4(acc1[0], acc1[1], acc1[2], acc1[3]);
        __syncthreads();   // (c) partials ready

        // ---- gate wave: reduce partials, gate math, fused {h,tag} store ----
        if (isGate) {
            const float* part = (const float*)part4;
            float s0 = 0.f, s1 = 0.f, s2 = 0.f;
#pragma unroll
            for (int k = 0; k < 16; ++k) {
                const float* pp = part + (k * 49) * 4;
                s0 += pp[(gjl << 2) + gb];
                s1 += pp[((16 + gjl) << 2) + gb];
                s2 += pp[((32 + gjl) << 2) + gb];
            }
            float hold = hlf[holdIdx];
            float rg = sigmoidf_(xr + s0 + bh_r);
            float zg = sigmoidf_(xz + s1 + bh_z);
            float ng = tanhf_(xn + rg * (s2 + bh_n));
            float hnew = (1.f - zg) * ng + zg * hold;
            bool m = t < glen;
            float hnext = m ? hnew : hold;
            y[((size_t)(b0 + gb) * Tdim + t) * Hdim + jg] = m ? hnew : 0.f;
            u32x2 pv;
            pv[0] = __float_as_uint(hnext);
            pv[1] = (unsigned)(t + 1);
            u32x2* dst = hb2 + ((size_t)((t + 1) & 1) << 14) + (bg << 11) + (gb << 9) + jg;
            asm volatile("global_store_dwordx2 %0, %1, off sc0 sc1"
                         :: "v"(dst), "v"(pv) : "memory");
            xr = xrn; xz = xzn; xn = xnn;
        }
        __syncthreads();   // (d) protect hlf/part4 from next iteration
    }
}

// ---------------------------------------------------------------------------
// fp32 NT-GEMM: C[m][n] = sum_k A[row(m)][k]*W[n][k] + bias[n]  (unchanged)
// ---------------------------------------------------------------------------
#define FMA4(c, a, b) { (c).x = fmaf((a), (b).x, (c).x); (c).y = fmaf((a), (b).y, (c).y); \
                        (c).z = fmaf((a), (b).z, (c).z); (c).w = fmaf((a), (b).w, (c).w); }

__global__ void __launch_bounds__(256)
gemm_xproj(const float* __restrict__ A,
           const float* __restrict__ W,     // [1536][512]
           const float* __restrict__ bias,  // [1536]
           float* __restrict__ C,           // [B*Tc][1536]
           int tcLog, int t0)
{
    __shared__ float As[16][132];
    __shared__ float Bs[16][132];
    const int tid = threadIdx.x;
    const int n0  = blockIdx.x << 7;
    const int m0  = blockIdx.y << 7;
    const int tx  = tid & 15;
    const int ty  = tid >> 4;

    const int mrow = tid >> 2;
    const int kcol = (tid & 3) << 2;
    const int Tcm1 = (1 << tcLog) - 1;

    int mg0 = m0 + mrow;
    int mg1 = m0 + 64 + mrow;
    size_t srow0 = (size_t)(mg0 >> tcLog) * Tdim + t0 + (mg0 & Tcm1);
    size_t srow1 = (size_t)(mg1 >> tcLog) * Tdim + t0 + (mg1 & Tcm1);
    const float* Ap0 = A + srow0 * Hdim + kcol;
    const float* Ap1 = A + srow1 * Hdim + kcol;
    const float* Wp0 = W + (size_t)(n0 + mrow) * Hdim + kcol;
    const float* Wp1 = W + (size_t)(n0 + 64 + mrow) * Hdim + kcol;

    float4 c00[4], c01[4], c10[4], c11[4];
#pragma unroll
    for (int i = 0; i < 4; ++i) {
        c00[i] = {0.f,0.f,0.f,0.f}; c01[i] = {0.f,0.f,0.f,0.f};
        c10[i] = {0.f,0.f,0.f,0.f}; c11[i] = {0.f,0.f,0.f,0.f};
    }

    float4 a0 = *(const float4*)(Ap0);
    float4 a1 = *(const float4*)(Ap1);
    float4 b0 = *(const float4*)(Wp0);
    float4 b1 = *(const float4*)(Wp1);

    for (int kt = 0; kt < 512; kt += 16) {
        __syncthreads();
        As[kcol+0][mrow] = a0.x; As[kcol+1][mrow] = a0.y;
        As[kcol+2][mrow] = a0.z; As[kcol+3][mrow] = a0.w;
        As[kcol+0][mrow+64] = a1.x; As[kcol+1][mrow+64] = a1.y;
        As[kcol+2][mrow+64] = a1.z; As[kcol+3][mrow+64] = a1.w;
        Bs[kcol+0][mrow] = b0.x; Bs[kcol+1][mrow] = b0.y;
        Bs[kcol+2][mrow] = b0.z; Bs[kcol+3][mrow] = b0.w;
        Bs[kcol+0][mrow+64] = b1.x; Bs[kcol+1][mrow+64] = b1.y;
        Bs[kcol+2][mrow+64] = b1.z; Bs[kcol+3][mrow+64] = b1.w;
        __syncthreads();
        if (kt + 16 < 512) {
            a0 = *(const float4*)(Ap0 + kt + 16);
            a1 = *(const float4*)(Ap1 + kt + 16);
            b0 = *(const float4*)(Wp0 + kt + 16);
            b1 = *(const float4*)(Wp1 + kt + 16);
        }
#pragma unroll
        for (int kk = 0; kk < 16; ++kk) {
            float4 aA = *(const float4*)&As[kk][ty * 4];
            float4 aB = *(const float4*)&As[kk][64 + ty * 4];
            float4 bA = *(const float4*)&Bs[kk][tx * 4];
            float4 bB = *(const float4*)&Bs[kk][64 + tx * 4];
            FMA4(c00[0], aA.x, bA); FMA4(c01[0], aA.x, bB);
            FMA4(c00[1], aA.y, bA); FMA4(c01[1], aA.y, bB);
            FMA4(c00[2], aA.z, bA); FMA4(c01[2], aA.z, bB);
            FMA4(c00[3], aA.w, bA); FMA4(c01[3], aA.w, bB);
            FMA4(c10[0], aB.x, bA); FMA4(c11[0], aB.x, bB);
            FMA4(c10[1], aB.y, bA); FMA4(c11[1], aB.y, bB);
            FMA4(c10[2], aB.z, bA); FMA4(c11[2], aB.z, bB);
            FMA4(c10[3], aB.w, bA); FMA4(c11[3], aB.w, bB);
        }
    }

    float4 biasA = *(const float4*)(bias + n0 + tx * 4);
    float4 biasB = *(const float4*)(bias + n0 + 64 + tx * 4);
#pragma unroll
    for (int i = 0; i < 4; ++i) {
        size_t row0 = (size_t)m0 + ty * 4 + i;
        size_t row1 = row0 + 64;
        float4 v;
        v.x = c00[i].x + biasA.x; v.y = c00[i].y + biasA.y;
        v.z = c00[i].z + biasA.z; v.w = c00[i].w + biasA.w;
        *(float4*)(C + row0 * 1536 + n0 + tx * 4) = v;
        v.x = c01[i].x + biasB.x; v.y = c01[i].y + biasB.y;
        v.z = c01[i].z + biasB.z; v.w = c01[i].w + biasB.w;
        *(float4*)(C + row0 * 1536 + n0 + 64 + tx * 4) = v;
        v.x = c10[i].x + biasA.x; v.y = c10[i].y + biasA.y;
        v.z = c10[i].z + biasA.z; v.w = c10[i].w + biasA.w;
        *(float4*)(C + row1 * 1536 + n0 + tx * 4) = v;
        v.x = c11[i].x + biasB.x; v.y = c11[i].y + biasB.y;
        v.z = c11[i].z + biasB.z; v.w = c11[i].w + biasB.w;
        *(float4*)(C + row1 * 1536 + n0 + 64 + tx * 4) = v;
    }
}

// ---------------------------------------------------------------------------
extern "C" void kernel_launch(void* const* d_in, const int* in_sizes, int n_in,
                              void* d_out, int out_size, void* d_ws, size_t ws_size,
                              hipStream_t stream) {
    (void)in_sizes; (void)n_in; (void)out_size;
    const float* x    = (const float*)d_in[0];
    const int*   lens = (const int*)d_in[1];
    const float* Wih0 = (const float*)d_in[2];
    const float* Whh0 = (const float*)d_in[3];
    const float* bih0 = (const float*)d_in[4];
    const float* bhh0 = (const float*)d_in[5];
    const float* Wih1 = (const float*)d_in[6];
    const float* Whh1 = (const float*)d_in[7];
    const float* bih1 = (const float*)d_in[8];
    const float* bhh1 = (const float*)d_in[9];
    float* out = (float*)d_out;

    // ws: [xp: B*Tc*1536 f32][hb2_0: 256KB][hb2_1: 256KB]
    // hb2 layer buffer: 2 ping-pong bufs x 8 groups x 2048 entries x 8B
    const size_t hb2_bytes  = (size_t)2 * 8 * 2048 * 8;      // 256 KB per layer
    const size_t ctrl_bytes = 2 * hb2_bytes;
    int Tc = 512;
    while (Tc > 4 && (size_t)Bdim * Tc * 1536 * 4 + ctrl_bytes > ws_size) Tc >>= 1;
    int tcLog = 31 - __builtin_clz((unsigned)Tc);
    size_t xp_bytes = (size_t)Bdim * Tc * 1536 * 4;

    float* xp = (float*)d_ws;
    char*  ctrl = (char*)d_ws + xp_bytes;
    u32x2* hb2_0 = (u32x2*)ctrl;
    u32x2* hb2_1 = (u32x2*)(ctrl + hb2_bytes);

    (void)hipMemsetAsync(ctrl, 0, ctrl_bytes, stream);

    const int nChunks = Tdim / Tc;
    for (int layer = 0; layer < 2; ++layer) {
        const float* src  = layer ? (const float*)out : x;
        const float* Wih  = layer ? Wih1 : Wih0;
        const float* bih  = layer ? bih1 : bih0;
        const float* Whh  = layer ? Whh1 : Whh0;
        const float* bhhp = layer ? bhh1 : bhh0;
        u32x2* hb2 = layer ? hb2_1 : hb2_0;

        for (int c = 0; c < nChunks; ++c) {
            int t0 = c * Tc;
            dim3 gg(12, (Bdim * Tc) >> 7);
            gemm_xproj<<<gg, dim3(256), 0, stream>>>(src, Wih, bih, xp, tcLog, t0);

            const float* a_xp  = xp;
            const float* a_whh = Whh;
            const float* a_bhh = bhhp;
            const int*   a_ln  = lens;
            float*       a_y   = out;
            u32x2*       a_hb  = hb2;
            int a_t0 = t0;
            int a_tc = Tc;
            void* args[] = { &a_xp, &a_whh, &a_bhh, &a_ln, &a_y, &a_hb, &a_t0, &a_tc };
            (void)hipLaunchCooperativeKernel((const void*)gru_scan, dim3(NWG),
                                             dim3(SCAN_THREADS), args, 0, stream);
        }
    }
}